// Round 6
// baseline (543.966 us; speedup 1.0000x reference)
//
#include <hip/hip_runtime.h>
#include <hip/hip_bf16.h>
#include <math.h>
#include <stdint.h>

// DiverseSiblingsSearch (lprobs (128,5,50257) f32, scores (128,5,10) f32, step=10)
//   lp = lprobs + scores[:,:,step-1,None]  (bias added BEFORE ordering, as reference)
//   per (b,beam): top-10 of lp over vocab; penalty -0.5*(rank+1); per b: top-10 of 50.
// Outputs concat as float32 values: scores[1280] | indices[1280] | beams[1280]
//
// Round-6 structure (r4/r5 lesson: serial tails starve the memory pipe; r5
// harness floor ~130 µs is fixed — only ~60 µs of kernel time is ours):
//   ONE fused kernel, grid (nc=9 chunks, 640 rows), 256 thr, 8 blocks/CU:
//     - 24 biased elems/thread in 6 float4 regs (one HBM read)
//     - tau = min of 16 group-maxes (16-lane groups): 4 shfl_xor max steps +
//       16-slot LDS + broadcast min. Valid: every group has >=1 elem >= tau
//       => chunk 10th-largest >= tau; >=min(16,len) survivors. E[surv]~54.
//     - filter from regs (1 cmp/elem) -> LDS append -> 256-thread rank-select
//       (keys unique) -> publish 10 keys/chunk via AGENT-scope atomic stores
//       (write-through; per-XCD L2s are not coherent)
//     - last of the 45 blocks per batch (AGENT fetch_add on zeroed counter)
//       runs the final: per-beam 90->10 rank-select (+penalty), then 50->10
//       with flat-pos tie-break (= jax top_k order). No spinning.
//   kernel_launch zeroes the 128 counters with hipMemsetAsync (capturable).

#define BS    256
#define KK    10
#define BEAM  5
#define NSLOT 6
#define CS    (BS * NSLOT * 4)   // 6144
#define CAP   1024               // survivor buffer (expected ~54/block)
#define FCAP  2048

typedef unsigned long long u64;

// monotone float <-> uint map (no NaNs in log_softmax output)
__device__ __forceinline__ uint32_t ford(float x) {
    uint32_t u = __float_as_uint(x);
    return (u & 0x80000000u) ? ~u : (u | 0x80000000u);
}
__device__ __forceinline__ float funord(uint32_t u) {
    return __uint_as_float((u & 0x80000000u) ? (u & 0x7fffffffu) : ~u);
}

// guarded sorted-desc insert (fallback kernel only)
__device__ __forceinline__ void insert10(u64 (&key)[KK], u64 k) {
    if (k > key[KK - 1]) {
#pragma unroll
        for (int j = KK - 1; j >= 1; --j)
            key[j] = (k > key[j - 1]) ? key[j - 1] : ((k > key[j]) ? k : key[j]);
        if (k > key[0]) key[0] = k;
    }
}

__global__ __launch_bounds__(BS, 8) void dss_fused(
    const float* __restrict__ lprobs,
    const float* __restrict__ scores,
    const int*   __restrict__ step_ptr,
    int vocab, int sdim, int nc, int bsz,
    int* __restrict__ counters,          // [bsz], zeroed by memsetAsync
    u64* __restrict__ ws_keys,           // [rows * nc * KK]
    float* __restrict__ out)
{
    const int chunk = blockIdx.x;
    const int row   = blockIdx.y;
    const int bb    = row / BEAM;
    const int tid   = threadIdx.x;
    const int lane  = tid & 63;
    const int step  = step_ptr[0];
    const float bias = scores[(size_t)row * sdim + (step - 1)];

    const int c0 = chunk * CS;
    int len = vocab - c0; if (len > CS) len = CS;
    const float* cp = lprobs + (size_t)row * vocab + c0;

    __shared__ u64   cand[CAP];
    __shared__ float sgrp[16];
    __shared__ int   s_cnt;
    __shared__ int   s_last;
    __shared__ u64   kbuf[BEAM * KK * 9];     // finisher: 450 keys
    __shared__ float pen [BEAM * KK];
    __shared__ int   pidx[BEAM * KK];

    // CS%4==0 -> every chunk of a row shares the row's dword misalignment
    int pre = (4 - (int)(((uintptr_t)cp >> 2) & 3)) & 3;
    if (pre > len) pre = len;
    const float4* g4 = (const float4*)(cp + pre);
    const int nvec = (len - pre) >> 2;
    const int done = pre + 4 * nvec;
    const int rem  = len - done;

    // ---- single pass: chunk into registers (biased) + per-thread max
    float4 v[NSLOT];
    float m = -INFINITY;
#pragma unroll
    for (int i = 0; i < NSLOT; ++i) {
        int idx = tid + (i << 8);
        if (idx < nvec) {
            float4 x = g4[idx];
            x.x += bias; x.y += bias; x.z += bias; x.w += bias;
            v[i] = x;
            m = fmaxf(m, fmaxf(fmaxf(x.x, x.y), fmaxf(x.z, x.w)));
        } else {
            v[i].x = -INFINITY; v[i].y = -INFINITY; v[i].z = -INFINITY; v[i].w = -INFINITY;
        }
    }
    // boundary leftovers: pre -> threads 0..2, rem -> threads 4..6 (one each)
    float xv = -INFINITY; int xi = -1;
    if (tid < pre)                        { xi = tid;            xv = cp[xi] + bias; }
    else if (tid >= 4 && tid < 4 + rem)   { xi = done + tid - 4; xv = cp[xi] + bias; }
    m = fmaxf(m, xv);

    if (tid == 0) s_cnt = 0;

    // ---- tau: min of 16 group-maxes (16-lane groups), block-wide
    float gm = m;
#pragma unroll
    for (int o = 1; o <= 8; o <<= 1) gm = fmaxf(gm, __shfl_xor(gm, o));
    if ((lane & 15) == 0) sgrp[(tid >> 6) * 4 + (lane >> 4)] = gm;
    __syncthreads();                          // also publishes s_cnt=0
    float tau = sgrp[0];
#pragma unroll
    for (int g = 1; g < 16; ++g) tau = fminf(tau, sgrp[g]);   // broadcast reads

    // ---- filter from registers (common path: 1 compare/element)
    auto app = [&](float x, int j) {          // j = chunk-local index
        if (j < len) {
            int p = atomicAdd(&s_cnt, 1);
            if (p < CAP) cand[p] = ((u64)ford(x) << 32) | (uint32_t)~(c0 + j);
        }
    };
#pragma unroll
    for (int i = 0; i < NSLOT; ++i) {
        int base = pre + ((tid + (i << 8)) << 2);
        if (v[i].x >= tau) app(v[i].x, base + 0);
        if (v[i].y >= tau) app(v[i].y, base + 1);
        if (v[i].z >= tau) app(v[i].z, base + 2);
        if (v[i].w >= tau) app(v[i].w, base + 3);
    }
    if (xi >= 0 && xv >= tau) app(xv, xi);
    __syncthreads();

    // ---- extraction: 256-thread rank-select (keys unique -> exact ranks);
    // publish with AGENT-scope atomic stores (visible across XCD L2s)
    int n = s_cnt; if (n > CAP) n = CAP;
    u64* outp = ws_keys + ((size_t)row * nc + chunk) * KK;
    for (int t2 = tid; t2 < n; t2 += BS) {
        u64 k = cand[t2];
        int rk = 0;
        for (int j = 0; j < n; ++j) rk += (cand[j] > k) ? 1 : 0;
        if (rk < KK)
            __hip_atomic_store(&outp[rk], k, __ATOMIC_RELEASE, __HIP_MEMORY_SCOPE_AGENT);
    }
    __syncthreads();    // drains vmcnt: all stores complete before the ticket

    // ---- last block of this batch finishes (45 blocks: 5 beams * 9 chunks)
    if (tid == 0) {
        int old = __hip_atomic_fetch_add(&counters[bb], 1, __ATOMIC_ACQ_REL,
                                         __HIP_MEMORY_SCOPE_AGENT);
        s_last = (old == BEAM * nc - 1) ? 1 : 0;
    }
    __syncthreads();
    if (!s_last) return;

    const int NC  = nc * KK;                  // 90
    const int tot = BEAM * NC;                // 450
    const u64* src = ws_keys + (size_t)bb * tot;
    for (int i = tid; i < tot; i += BS)
        kbuf[i] = __hip_atomic_load(&src[i], __ATOMIC_RELAXED, __HIP_MEMORY_SCOPE_AGENT);
    __syncthreads();

    // phase 1: per-beam top-10 via rank-select (keys unique within a beam)
    for (int i = tid; i < tot; i += BS) {
        int beam = i / NC;
        u64 k = kbuf[i];
        const u64* kb = kbuf + beam * NC;
        int r = 0;
        for (int j = 0; j < NC; ++j) r += (kb[j] > k) ? 1 : 0;
        if (r < KK) {
            pen [beam * KK + r] = funord((uint32_t)(k >> 32)) - 0.5f * (float)(r + 1);
            pidx[beam * KK + r] = (int)~(uint32_t)k;
        }
    }
    __syncthreads();

    // phase 2: top-10 of 50, ties -> lowest flat position (jax top_k order)
    if (tid < BEAM * KK) {
        float p = pen[tid];
        int r = 0;
        for (int j = 0; j < BEAM * KK; ++j) {
            float q = pen[j];
            r += (q > p || (q == p && j < tid)) ? 1 : 0;
        }
        if (r < KK) {
            out[                       bb * KK + r] = p;
            out[(size_t)bsz * KK     + bb * KK + r] = (float)pidx[tid];
            out[(size_t)2 * bsz * KK + bb * KK + r] = (float)(tid / KK);
        }
    }
}

// ---------------- fallback path (tiny ws): round-2-proven two-kernel version
__global__ __launch_bounds__(BS) void dss_row_topk(
    const float* __restrict__ lprobs,
    const float* __restrict__ scores,
    const int*   __restrict__ step_ptr,
    int vocab, int sdim,
    u64* __restrict__ ws_keys)
{
    const int row = blockIdx.x;
    const int tid = threadIdx.x;
    const int step = step_ptr[0];
    const float bias = scores[(size_t)row * sdim + (step - 1)];
    const float* rp = lprobs + (size_t)row * vocab;

    __shared__ u64  cand[FCAP];
    __shared__ u64  skey[BS * KK];
    __shared__ int  cnt;
    __shared__ float sh_tau;

    int pre = (4 - (int)(((uintptr_t)rp >> 2) & 3)) & 3;
    if (pre > vocab) pre = vocab;
    const float4* p4 = (const float4*)(rp + pre);
    const int nvec = (vocab - pre) >> 2;
    const int done = pre + 4 * nvec;
    const int rem  = vocab - done;

    float m = -INFINITY;
    if (tid < pre) m = rp[tid] + bias;
    for (int t = tid; t < nvec; t += BS) {
        float4 x = p4[t];
        m = fmaxf(m, fmaxf(fmaxf(x.x + bias, x.y + bias), fmaxf(x.z + bias, x.w + bias)));
    }
    if (tid < rem) m = fmaxf(m, rp[done + tid] + bias);

    skey[tid * KK] = ((u64)ford(m) << 32) | (uint32_t)~tid;
#pragma unroll
    for (int j = 1; j < KK; ++j) skey[tid * KK + j] = 0;
    if (tid == 0) cnt = 0;
    __syncthreads();
    for (int off = BS / 2; off >= 1; off >>= 1) {
        if (tid < off) {
            const int pa = tid * KK, pb = (tid + off) * KK;
            u64 mk[KK]; int ia = 0, ib = 0;
#pragma unroll
            for (int j = 0; j < KK; ++j) {
                u64 ka = skey[pa + ia], kb = skey[pb + ib];
                bool tA = (ka >= kb); mk[j] = tA ? ka : kb;
                if (tA) ++ia; else ++ib;
            }
#pragma unroll
            for (int j = 0; j < KK; ++j) skey[pa + j] = mk[j];
        }
        __syncthreads();
    }
    if (tid == 0) sh_tau = funord((uint32_t)(skey[9] >> 32));
    __syncthreads();
    const float tau = sh_tau;

    auto app = [&](float x, int i) {
        if (x >= tau) {
            int p = atomicAdd(&cnt, 1);
            if (p < FCAP) cand[p] = ((u64)ford(x) << 32) | (uint32_t)~i;
        }
    };
    if (tid < pre) app(rp[tid] + bias, tid);
    for (int t = tid; t < nvec; t += BS) {
        float4 x = p4[t];
        int base = pre + 4 * t;
        app(x.x + bias, base + 0); app(x.y + bias, base + 1);
        app(x.z + bias, base + 2); app(x.w + bias, base + 3);
    }
    if (tid < rem) app(rp[done + tid] + bias, done + tid);
    __syncthreads();

    const int n = (cnt < FCAP) ? cnt : FCAP;
    {
        u64 key[KK];
#pragma unroll
        for (int j = 0; j < KK; ++j) key[j] = 0;
        for (int i = tid; i < n; i += BS) insert10(key, cand[i]);
#pragma unroll
        for (int j = 0; j < KK; ++j) skey[tid * KK + j] = key[j];
    }
    __syncthreads();
    for (int off = BS / 2; off >= 1; off >>= 1) {
        if (tid < off) {
            const int pa = tid * KK, pb = (tid + off) * KK;
            u64 mk[KK]; int ia = 0, ib = 0;
#pragma unroll
            for (int j = 0; j < KK; ++j) {
                u64 ka = skey[pa + ia], kb = skey[pb + ib];
                bool tA = (ka >= kb); mk[j] = tA ? ka : kb;
                if (tA) ++ia; else ++ib;
            }
#pragma unroll
            for (int j = 0; j < KK; ++j) skey[pa + j] = mk[j];
        }
        __syncthreads();
    }
    if (tid < KK) ws_keys[(size_t)row * KK + tid] = skey[tid];
}

__global__ __launch_bounds__(512) void dss_final(
    const u64* __restrict__ ws_keys,
    float* __restrict__ out, int bsz, int nc)
{
    const int b = blockIdx.x;
    const int t = threadIdx.x;
    const int NC  = nc * KK;
    const int tot = BEAM * NC;

    __shared__ u64  kbuf[BEAM * KK * 9];
    __shared__ float pen[BEAM * KK];
    __shared__ int   pidx[BEAM * KK];

    for (int i = t; i < tot; i += 512) kbuf[i] = ws_keys[(size_t)b * tot + i];
    __syncthreads();

    if (t < tot) {
        int beam = t / NC;
        u64 k = kbuf[t];
        const u64* kb = kbuf + beam * NC;
        int r = 0;
        for (int j = 0; j < NC; ++j) r += (kb[j] > k) ? 1 : 0;
        if (r < KK) {
            pen [beam * KK + r] = funord((uint32_t)(k >> 32)) - 0.5f * (float)(r + 1);
            pidx[beam * KK + r] = (int)~(uint32_t)k;
        }
    }
    __syncthreads();

    if (t < BEAM * KK) {
        float p = pen[t];
        int r = 0;
        for (int j = 0; j < BEAM * KK; ++j) {
            float q = pen[j];
            r += (q > p || (q == p && j < t)) ? 1 : 0;
        }
        if (r < KK) {
            out[              b * KK + r] = p;
            out[(size_t)bsz * KK     + b * KK + r] = (float)pidx[t];
            out[(size_t)2 * bsz * KK + b * KK + r] = (float)(t / KK);
        }
    }
}

extern "C" void kernel_launch(void* const* d_in, const int* in_sizes, int n_in,
                              void* d_out, int out_size, void* d_ws, size_t ws_size,
                              hipStream_t stream)
{
    const float* lprobs = (const float*)d_in[0];
    const float* scores = (const float*)d_in[1];
    const int*   step   = (const int*)d_in[2];

    const int bsz   = 128;
    const int rows  = bsz * BEAM;                 // 640
    const int vocab = in_sizes[0] / rows;         // 50257
    const int sdim  = in_sizes[1] / rows;         // 10

    int nc = (vocab + CS - 1) / CS;               // 9
    if (nc > 9) nc = 9;                           // kbuf sizing bound

    const size_t need = 1024 + (size_t)rows * nc * KK * sizeof(u64);
    if (nc > 1 && ws_size >= need) {
        int* counters = (int*)d_ws;               // [bsz] + pad to 1 KB
        u64* ws_keys  = (u64*)((char*)d_ws + 1024);
        hipMemsetAsync(d_ws, 0, 1024, stream);    // zero counters (capturable)
        dss_fused<<<dim3(nc, rows), BS, 0, stream>>>(
            lprobs, scores, step, vocab, sdim, nc, bsz,
            counters, ws_keys, (float*)d_out);
    } else {
        u64* ws_keys = (u64*)d_ws;
        dss_row_topk<<<rows, BS, 0, stream>>>(lprobs, scores, step, vocab, sdim, ws_keys);
        dss_final<<<bsz, 512, 0, stream>>>(ws_keys, (float*)d_out, bsz, 1);
    }
}

// Round 7
// 197.864 us; speedup vs baseline: 2.7492x; 2.7492x over previous
//
#include <hip/hip_runtime.h>
#include <hip/hip_bf16.h>
#include <math.h>
#include <stdint.h>

// DiverseSiblingsSearch (lprobs (128,5,50257) f32, scores (128,5,10) f32, step=10)
//   lp = lprobs + scores[:,:,step-1,None]  (bias added BEFORE ordering, as reference)
//   per (b,beam): top-10 of lp over vocab; penalty -0.5*(rank+1); per b: top-10 of 50.
// Outputs concat as float32 values: scores[1280] | indices[1280] | beams[1280]
//
// Round-7: r5 two-kernel structure (plain stores; r6's agent-scope atomic
// fusion caused L2-writeback storms -> 3% VALUBusy, reverted) + r6's cheap
// tau and the unguarded fast-path loads.
//   Kernel 1, grid (8 chunks, 640 rows), 256 thr:
//     - 28 biased elems/thread in 7 float4 regs (one HBM read, no staging)
//     - tau = min of 16 group-maxes (16-lane groups, 4 shfl_xor + 16-slot LDS
//       + broadcast min). Valid: each group's max elem >= tau => >=16
//       survivors, chunk 10th-largest >= tau. E[surv] ~ 16*H16 ~ 54.
//     - filter from regs (1 cmp/elem) -> LDS append -> 256-thread rank-select
//       (keys unique -> exact), rank<10 -> plain global store to ws.
//   Kernel 2 (dss_final): per-beam 80->10 rank-select (+penalty), then 50->10
//   with flat-pos tie-break (= jax top_k order).

#define BS    256
#define KK    10
#define BEAM  5
#define NSLOT 7
#define CS    (BS * NSLOT * 4)   // 7168
#define CAP   1024               // survivor buffer (expected ~54/block)
#define FCAP  2048

typedef unsigned long long u64;

// monotone float <-> uint map (no NaNs in log_softmax output)
__device__ __forceinline__ uint32_t ford(float x) {
    uint32_t u = __float_as_uint(x);
    return (u & 0x80000000u) ? ~u : (u | 0x80000000u);
}
__device__ __forceinline__ float funord(uint32_t u) {
    return __uint_as_float((u & 0x80000000u) ? (u & 0x7fffffffu) : ~u);
}

// guarded sorted-desc insert (fallback kernel only)
__device__ __forceinline__ void insert10(u64 (&key)[KK], u64 k) {
    if (k > key[KK - 1]) {
#pragma unroll
        for (int j = KK - 1; j >= 1; --j)
            key[j] = (k > key[j - 1]) ? key[j - 1] : ((k > key[j]) ? k : key[j]);
        if (k > key[0]) key[0] = k;
    }
}

__global__ __launch_bounds__(BS) void dss_chunk_topk(
    const float* __restrict__ lprobs,
    const float* __restrict__ scores,
    const int*   __restrict__ step_ptr,
    int vocab, int sdim, int nc,
    u64* __restrict__ ws_keys)
{
    const int chunk = blockIdx.x;
    const int row   = blockIdx.y;
    const int tid   = threadIdx.x;
    const int lane  = tid & 63;
    const int step  = step_ptr[0];
    const float bias = scores[(size_t)row * sdim + (step - 1)];

    const int c0 = chunk * CS;
    int len = vocab - c0; if (len > CS) len = CS;
    const float* cp = lprobs + (size_t)row * vocab + c0;

    __shared__ u64   cand[CAP];
    __shared__ float sgrp[16];
    __shared__ int   s_cnt;

    // CS%4==0 -> every chunk of a row shares the row's dword misalignment
    int pre = (4 - (int)(((uintptr_t)cp >> 2) & 3)) & 3;
    if (pre > len) pre = len;
    const float4* g4 = (const float4*)(cp + pre);
    const int nvec = (len - pre) >> 2;
    const int done = pre + 4 * nvec;
    const int rem  = len - done;

    // ---- single pass: chunk into registers (biased) + per-thread max
    float4 v[NSLOT];
    float m = -INFINITY;
    if (nvec == NSLOT * BS) {
        // full chunk: unguarded back-to-back dwordx4 loads (max MLP)
#pragma unroll
        for (int i = 0; i < NSLOT; ++i) v[i] = g4[tid + (i << 8)];
#pragma unroll
        for (int i = 0; i < NSLOT; ++i) {
            v[i].x += bias; v[i].y += bias; v[i].z += bias; v[i].w += bias;
            m = fmaxf(m, fmaxf(fmaxf(v[i].x, v[i].y), fmaxf(v[i].z, v[i].w)));
        }
    } else {
#pragma unroll
        for (int i = 0; i < NSLOT; ++i) {
            int idx = tid + (i << 8);
            if (idx < nvec) {
                float4 x = g4[idx];
                x.x += bias; x.y += bias; x.z += bias; x.w += bias;
                v[i] = x;
                m = fmaxf(m, fmaxf(fmaxf(x.x, x.y), fmaxf(x.z, x.w)));
            } else {
                v[i].x = -INFINITY; v[i].y = -INFINITY; v[i].z = -INFINITY; v[i].w = -INFINITY;
            }
        }
    }
    // boundary leftovers: pre -> threads 0..2, rem -> threads 4..6 (one each)
    float xv = -INFINITY; int xi = -1;
    if (tid < pre)                        { xi = tid;            xv = cp[xi] + bias; }
    else if (tid >= 4 && tid < 4 + rem)   { xi = done + tid - 4; xv = cp[xi] + bias; }
    m = fmaxf(m, xv);

    if (tid == 0) s_cnt = 0;

    // ---- tau: min of 16 group-maxes (16-lane groups), block-wide
    float gm = m;
#pragma unroll
    for (int o = 1; o <= 8; o <<= 1) gm = fmaxf(gm, __shfl_xor(gm, o));
    if ((lane & 15) == 0) sgrp[(tid >> 6) * 4 + (lane >> 4)] = gm;
    __syncthreads();                          // also publishes s_cnt=0
    float tau = sgrp[0];
#pragma unroll
    for (int g = 1; g < 16; ++g) tau = fminf(tau, sgrp[g]);   // broadcast reads

    // ---- filter from registers (common path: 1 compare/element)
    auto app = [&](float x, int j) {          // j = chunk-local index
        if (j < len) {
            int p = atomicAdd(&s_cnt, 1);
            if (p < CAP) cand[p] = ((u64)ford(x) << 32) | (uint32_t)~(c0 + j);
        }
    };
#pragma unroll
    for (int i = 0; i < NSLOT; ++i) {
        int base = pre + ((tid + (i << 8)) << 2);
        if (v[i].x >= tau) app(v[i].x, base + 0);
        if (v[i].y >= tau) app(v[i].y, base + 1);
        if (v[i].z >= tau) app(v[i].z, base + 2);
        if (v[i].w >= tau) app(v[i].w, base + 3);
    }
    if (xi >= 0 && xv >= tau) app(xv, xi);
    __syncthreads();

    // ---- extraction: 256-thread rank-select (keys unique -> exact ranks)
    int n = s_cnt; if (n > CAP) n = CAP;
    u64* outp = ws_keys + ((size_t)row * nc + chunk) * KK;
    if (tid < KK && tid >= n) outp[tid] = 0;  // pathological-shape guard
    for (int t2 = tid; t2 < n; t2 += BS) {
        u64 k = cand[t2];
        int rk = 0;
        for (int j = 0; j < n; ++j) rk += (cand[j] > k) ? 1 : 0;  // broadcast
        if (rk < KK) outp[rk] = k;
    }
}

// per b: rank-select per beam (nc*10 -> 10, apply penalty), then 50 -> 10
__global__ __launch_bounds__(512) void dss_final(
    const u64* __restrict__ ws_keys,
    float* __restrict__ out, int bsz, int nc)
{
    const int b = blockIdx.x;
    const int t = threadIdx.x;
    const int NC  = nc * KK;            // <= 80
    const int tot = BEAM * NC;          // <= 400

    __shared__ u64  kbuf[BEAM * KK * 8];
    __shared__ float pen[BEAM * KK];
    __shared__ int   pidx[BEAM * KK];

    for (int i = t; i < tot; i += 512) kbuf[i] = ws_keys[(size_t)b * tot + i];
    __syncthreads();

    // phase 1: per-beam top-10 via rank-select (keys unique within a beam)
    if (t < tot) {
        int beam = t / NC;
        u64 k = kbuf[t];
        const u64* kb = kbuf + beam * NC;
        int r = 0;
        for (int j = 0; j < NC; ++j) r += (kb[j] > k) ? 1 : 0;
        if (r < KK) {
            pen [beam * KK + r] = funord((uint32_t)(k >> 32)) - 0.5f * (float)(r + 1);
            pidx[beam * KK + r] = (int)~(uint32_t)k;
        }
    }
    __syncthreads();

    // phase 2: top-10 of 50, ties -> lowest flat position (jax top_k order)
    if (t < BEAM * KK) {
        float p = pen[t];
        int r = 0;
        for (int j = 0; j < BEAM * KK; ++j) {
            float q = pen[j];
            r += (q > p || (q == p && j < t)) ? 1 : 0;
        }
        if (r < KK) {
            out[              b * KK + r] = p;
            out[(size_t)bsz * KK     + b * KK + r] = (float)pidx[t];
            out[(size_t)2 * bsz * KK + b * KK + r] = (float)(t / KK);
        }
    }
}

// ---------------- fallback (whole-row, two global passes) for tiny ws
__global__ __launch_bounds__(BS) void dss_row_topk(
    const float* __restrict__ lprobs,
    const float* __restrict__ scores,
    const int*   __restrict__ step_ptr,
    int vocab, int sdim,
    u64* __restrict__ ws_keys)
{
    const int row = blockIdx.x;
    const int tid = threadIdx.x;
    const int step = step_ptr[0];
    const float bias = scores[(size_t)row * sdim + (step - 1)];
    const float* rp = lprobs + (size_t)row * vocab;

    __shared__ u64  cand[FCAP];
    __shared__ u64  skey[BS * KK];
    __shared__ int  cnt;
    __shared__ float sh_tau;

    int pre = (4 - (int)(((uintptr_t)rp >> 2) & 3)) & 3;
    if (pre > vocab) pre = vocab;
    const float4* p4 = (const float4*)(rp + pre);
    const int nvec = (vocab - pre) >> 2;
    const int done = pre + 4 * nvec;
    const int rem  = vocab - done;

    float m = -INFINITY;
    if (tid < pre) m = rp[tid] + bias;
    for (int t = tid; t < nvec; t += BS) {
        float4 x = p4[t];
        m = fmaxf(m, fmaxf(fmaxf(x.x + bias, x.y + bias), fmaxf(x.z + bias, x.w + bias)));
    }
    if (tid < rem) m = fmaxf(m, rp[done + tid] + bias);

    skey[tid * KK] = ((u64)ford(m) << 32) | (uint32_t)~tid;
#pragma unroll
    for (int j = 1; j < KK; ++j) skey[tid * KK + j] = 0;
    if (tid == 0) cnt = 0;
    __syncthreads();
    for (int off = BS / 2; off >= 1; off >>= 1) {
        if (tid < off) {
            const int pa = tid * KK, pb = (tid + off) * KK;
            u64 mk[KK]; int ia = 0, ib = 0;
#pragma unroll
            for (int j = 0; j < KK; ++j) {
                u64 ka = skey[pa + ia], kb = skey[pb + ib];
                bool tA = (ka >= kb); mk[j] = tA ? ka : kb;
                if (tA) ++ia; else ++ib;
            }
#pragma unroll
            for (int j = 0; j < KK; ++j) skey[pa + j] = mk[j];
        }
        __syncthreads();
    }
    if (tid == 0) sh_tau = funord((uint32_t)(skey[9] >> 32));
    __syncthreads();
    const float tau = sh_tau;

    auto app = [&](float x, int i) {
        if (x >= tau) {
            int p = atomicAdd(&cnt, 1);
            if (p < FCAP) cand[p] = ((u64)ford(x) << 32) | (uint32_t)~i;
        }
    };
    if (tid < pre) app(rp[tid] + bias, tid);
    for (int t = tid; t < nvec; t += BS) {
        float4 x = p4[t];
        int base = pre + 4 * t;
        app(x.x + bias, base + 0); app(x.y + bias, base + 1);
        app(x.z + bias, base + 2); app(x.w + bias, base + 3);
    }
    if (tid < rem) app(rp[done + tid] + bias, done + tid);
    __syncthreads();

    const int n = (cnt < FCAP) ? cnt : FCAP;
    {
        u64 key[KK];
#pragma unroll
        for (int j = 0; j < KK; ++j) key[j] = 0;
        for (int i = tid; i < n; i += BS) insert10(key, cand[i]);
#pragma unroll
        for (int j = 0; j < KK; ++j) skey[tid * KK + j] = key[j];
    }
    __syncthreads();
    for (int off = BS / 2; off >= 1; off >>= 1) {
        if (tid < off) {
            const int pa = tid * KK, pb = (tid + off) * KK;
            u64 mk[KK]; int ia = 0, ib = 0;
#pragma unroll
            for (int j = 0; j < KK; ++j) {
                u64 ka = skey[pa + ia], kb = skey[pb + ib];
                bool tA = (ka >= kb); mk[j] = tA ? ka : kb;
                if (tA) ++ia; else ++ib;
            }
#pragma unroll
            for (int j = 0; j < KK; ++j) skey[pa + j] = mk[j];
        }
        __syncthreads();
    }
    if (tid < KK) ws_keys[(size_t)row * KK + tid] = skey[tid];
}

extern "C" void kernel_launch(void* const* d_in, const int* in_sizes, int n_in,
                              void* d_out, int out_size, void* d_ws, size_t ws_size,
                              hipStream_t stream)
{
    const float* lprobs = (const float*)d_in[0];
    const float* scores = (const float*)d_in[1];
    const int*   step   = (const int*)d_in[2];

    const int bsz   = 128;
    const int rows  = bsz * BEAM;                 // 640
    const int vocab = in_sizes[0] / rows;         // 50257
    const int sdim  = in_sizes[1] / rows;         // 10

    u64* ws_keys = (u64*)d_ws;

    int nc = (vocab + CS - 1) / CS;               // 8
    if (nc > 8) nc = 8;                           // kbuf sizing bound
    if (ws_size < (size_t)rows * nc * KK * sizeof(u64)) nc = 1;

    if (nc > 1) {
        dss_chunk_topk<<<dim3(nc, rows), BS, 0, stream>>>(
            lprobs, scores, step, vocab, sdim, nc, ws_keys);
    } else {
        dss_row_topk<<<rows, BS, 0, stream>>>(lprobs, scores, step, vocab, sdim, ws_keys);
    }
    dss_final<<<bsz, 512, 0, stream>>>(ws_keys, (float*)d_out, bsz, nc);
}